// Round 14
// baseline (204.694 us; speedup 1.0000x reference)
//
#include <hip/hip_runtime.h>
#include <hip/hip_bf16.h>

typedef short short8 __attribute__((ext_vector_type(8)));
typedef float f32x4 __attribute__((ext_vector_type(4)));

#define LN_EPS 1e-5f
#define NBLK 512   // chunk blocks for hist/scatter (2 blocks/CU); must match scan1

__device__ __forceinline__ unsigned short f2bf(float f) {
    unsigned int u = __builtin_bit_cast(unsigned int, f);
    unsigned int r = (u + 0x7FFFu + ((u >> 16) & 1u)) >> 16;
    return (unsigned short)r;
}
__device__ __forceinline__ float bf_lo(unsigned int v) {
    return __builtin_bit_cast(float, v << 16);
}
__device__ __forceinline__ float bf_hi(unsigned int v) {
    return __builtin_bit_cast(float, v & 0xFFFF0000u);
}

__device__ __forceinline__ bool edges_are_i64(const int* ei) {
    return ((ei[1] | ei[3] | ei[5] | ei[7]) == 0);
}

// ---------------- shared device bodies --------------------------------------
__device__ __forceinline__ void do_hist(
    const int* __restrict__ ei, int* __restrict__ BBC, int E, int chunk,
    int blk, int t, int* hist)
{
    hist[t] = 0;
    __syncthreads();
    int beg = blk * chunk;
    int end = min(E, beg + chunk);
    if (edges_are_i64(ei)) {
        const long long* e64 = (const long long*)ei;
        for (int e = beg + t; e < end; e += 256)
            atomicAdd(&hist[((int)e64[E + e]) >> 8], 1);
    } else {
        for (int e = beg + t; e < end; e += 256)
            atomicAdd(&hist[ei[E + e] >> 8], 1);
    }
    __syncthreads();
    BBC[t * NBLK + blk] = hist[t];
}

__device__ __forceinline__ void do_prep(
    const float* __restrict__ W1, const float* __restrict__ W2,
    const float* __restrict__ W3, const float* __restrict__ W4,
    unsigned short* __restrict__ wt1, unsigned short* __restrict__ wt2,
    unsigned short* __restrict__ wt3, unsigned short* __restrict__ wt4,
    const float4* __restrict__ x4, uint4* __restrict__ xb4, int total8,
    int idx)
{
    if (idx < 32768) {                       // W1: 256x128
        int k = idx >> 7, n = idx & 127;
        wt1[n * 256 + k] = f2bf(W1[idx]);
    } else if (idx < 49152) {                // W2: 128x128
        int j = idx - 32768; int k = j >> 7, n = j & 127;
        wt2[n * 128 + k] = f2bf(W2[j]);
    } else if (idx < 65536) {                // W3
        int j = idx - 49152; int k = j >> 7, n = j & 127;
        wt3[n * 128 + k] = f2bf(W3[j]);
    } else if (idx < 81920) {                // W4
        int j = idx - 65536; int k = j >> 7, n = j & 127;
        wt4[n * 128 + k] = f2bf(W4[j]);
    } else {
        int i = idx - 81920;
        if (i < total8) {                    // x -> bf16 (8 elems per thread)
            float4 a = x4[i * 2], b = x4[i * 2 + 1];
            uint4 o;
            o.x = (unsigned int)f2bf(a.x) | ((unsigned int)f2bf(a.y) << 16);
            o.y = (unsigned int)f2bf(a.z) | ((unsigned int)f2bf(a.w) << 16);
            o.z = (unsigned int)f2bf(b.x) | ((unsigned int)f2bf(b.y) << 16);
            o.w = (unsigned int)f2bf(b.z) | ((unsigned int)f2bf(b.w) << 16);
            xb4[i] = o;
        }
    }
}

// ---------------- merged: hist (blocks < NBLK) + prep (blocks >= NBLK) ------
__global__ __launch_bounds__(256) void hist_prep_kernel(
    const int* __restrict__ ei, int* __restrict__ BBC, int E, int chunk,
    const float* __restrict__ W1, const float* __restrict__ W2,
    const float* __restrict__ W3, const float* __restrict__ W4,
    unsigned short* __restrict__ wt1, unsigned short* __restrict__ wt2,
    unsigned short* __restrict__ wt3, unsigned short* __restrict__ wt4,
    const float4* __restrict__ x4, uint4* __restrict__ xb4, int total8)
{
    __shared__ int sh[256];
    int t = threadIdx.x;
    if (blockIdx.x < NBLK) {
        do_hist(ei, BBC, E, chunk, blockIdx.x, t, sh);
    } else {
        do_prep(W1, W2, W3, W4, wt1, wt2, wt3, wt4, x4, xb4, total8,
                (blockIdx.x - NBLK) * 256 + t);
    }
}

// ---------------- x fp32 -> bf16 (tier-1 only: runs after sort) -------------
__global__ __launch_bounds__(256) void xcvt_kernel(
    const float4* __restrict__ x4, uint4* __restrict__ xb4, int total8)
{
    int i = blockIdx.x * 256 + threadIdx.x;
    if (i >= total8) return;
    float4 a = x4[i * 2], b = x4[i * 2 + 1];
    uint4 o;
    o.x = (unsigned int)f2bf(a.x) | ((unsigned int)f2bf(a.y) << 16);
    o.y = (unsigned int)f2bf(a.z) | ((unsigned int)f2bf(a.w) << 16);
    o.z = (unsigned int)f2bf(b.x) | ((unsigned int)f2bf(b.y) << 16);
    o.w = (unsigned int)f2bf(b.z) | ((unsigned int)f2bf(b.w) << 16);
    xb4[i] = o;
}

// S1: per-bucket exclusive scan across NBLK=512 chunk counts (2 per thread)
__global__ __launch_bounds__(256) void bucket_scan1_kernel(
    const int* __restrict__ BBC, int* __restrict__ BBL, int* __restrict__ bucketTotal)
{
    __shared__ int sd[256];
    int t = threadIdx.x, b = blockIdx.x;
    int v0 = BBC[b * NBLK + 2 * t];
    int v1 = BBC[b * NBLK + 2 * t + 1];
    int pair = v0 + v1;
    sd[t] = pair;
    __syncthreads();
    for (int d = 1; d < 256; d <<= 1) {
        int add = (t >= d) ? sd[t - d] : 0;
        __syncthreads();
        sd[t] += add;
        __syncthreads();
    }
    int excl = sd[t] - pair;                 // sum of chunks < 2t
    BBL[b * NBLK + 2 * t]     = excl;
    BBL[b * NBLK + 2 * t + 1] = excl + v0;
    if (t == 255) bucketTotal[b] = sd[255];
}

// B: scatter edges into coarse-bucket regions (LDS cursors, plain stores)
//    bucket bases recomputed in-LDS from bucketTotal (scan2 folded in).
//    packed word = sender (24 bits) | r_local (top 8 bits)
__global__ __launch_bounds__(256) void bucket_scatter_kernel(
    const int* __restrict__ ei, const int* __restrict__ BBL,
    const int* __restrict__ bucketTotal, unsigned int* __restrict__ packed,
    int E, int chunk)
{
    __shared__ int cur[256];
    __shared__ int sd[256];
    int t = threadIdx.x, blk = blockIdx.x;
    int v = bucketTotal[t];
    sd[t] = v;
    __syncthreads();
    for (int d = 1; d < 256; d <<= 1) {
        int add = (t >= d) ? sd[t - d] : 0;
        __syncthreads();
        sd[t] += add;
        __syncthreads();
    }
    cur[t] = (sd[t] - v) + BBL[t * NBLK + blk];  // bucketBase[t] + within-bucket off
    __syncthreads();
    int beg = blk * chunk;
    int end = min(E, beg + chunk);
    if (edges_are_i64(ei)) {
        const long long* e64 = (const long long*)ei;
        for (int e = beg + t; e < end; e += 256) {
            int s = (int)e64[e], r = (int)e64[E + e];
            int pos = atomicAdd(&cur[r >> 8], 1);
            packed[pos] = (unsigned int)s | ((unsigned int)(r & 255) << 24);
        }
    } else {
        for (int e = beg + t; e < end; e += 256) {
            int s = ei[e], r = ei[E + e];
            int pos = atomicAdd(&cur[r >> 8], 1);
            packed[pos] = (unsigned int)s | ((unsigned int)(r & 255) << 24);
        }
    }
}

// C: per-bucket fine counting sort -> offsets[] and sorted[] (senders)
//    bucket base recomputed in-LDS from bucketTotal (scan2 folded in).
__global__ __launch_bounds__(256) void bucket_sort_kernel(
    const unsigned int* __restrict__ packed, const int* __restrict__ bucketTotal,
    int* __restrict__ offsets, int* __restrict__ sorted, int N)
{
    __shared__ int hist[256];
    __shared__ int sd[256];
    __shared__ int base[256];
    int t = threadIdx.x, b = blockIdx.x;
    int bv = bucketTotal[t];
    sd[t] = bv;
    __syncthreads();
    for (int d = 1; d < 256; d <<= 1) {
        int add = (t >= d) ? sd[t - d] : 0;
        __syncthreads();
        sd[t] += add;
        __syncthreads();
    }
    base[t] = sd[t] - bv;                    // exclusive bucket base
    __syncthreads();
    int beg = base[b];
    int end = beg + bucketTotal[b];
    hist[t] = 0;
    __syncthreads();
    for (int i = beg + t; i < end; i += 256)
        atomicAdd(&hist[packed[i] >> 24], 1);
    __syncthreads();
    int v = hist[t];
    sd[t] = v;
    __syncthreads();
    for (int d = 1; d < 256; d <<= 1) {
        int add = (t >= d) ? sd[t - d] : 0;
        __syncthreads();
        sd[t] += add;
        __syncthreads();
    }
    int excl = sd[t] - v;
    int idx = b * 256 + t;
    if (idx <= N) offsets[idx] = beg + excl;   // idx==N lands here too (== E)
    hist[t] = excl;                            // reuse as LDS cursor
    __syncthreads();
    for (int i = beg + t; i < end; i += 256) {
        unsigned int p = packed[i];
        int rl = (int)(p >> 24);
        int pos = beg + atomicAdd(&hist[rl], 1);
        sorted[pos] = (int)(p & 0xFFFFFFu);
    }
}

// ---------------- atomic-free segmented aggregation ----------------
template<bool BF>
__global__ __launch_bounds__(256) void aggregate_kernel(
    const void* __restrict__ xsrc, const int* __restrict__ offsets,
    const int* __restrict__ sorted, unsigned int* __restrict__ aggb, int N)
{
    int wave = threadIdx.x >> 6, lane = threadIdx.x & 63;
    int r = blockIdx.x * 4 + wave;
    if (r >= N) return;
    int beg = offsets[r], end = offsets[r + 1];
    const unsigned int* xb = (const unsigned int*)xsrc;
    const float2* x2 = (const float2*)xsrc;
    float ax0 = 0, ay0 = 0, ax1 = 0, ay1 = 0;
    float ax2 = 0, ay2 = 0, ax3 = 0, ay3 = 0;
    int i = beg;
    for (; i + 8 <= end; i += 8) {
        int s0 = sorted[i + 0];
        int s1 = sorted[i + 1];
        int s2 = sorted[i + 2];
        int s3 = sorted[i + 3];
        int s4 = sorted[i + 4];
        int s5 = sorted[i + 5];
        int s6 = sorted[i + 6];
        int s7 = sorted[i + 7];
        if constexpr (BF) {
            unsigned int v0 = xb[(size_t)s0 * 64 + lane];
            unsigned int v1 = xb[(size_t)s1 * 64 + lane];
            unsigned int v2 = xb[(size_t)s2 * 64 + lane];
            unsigned int v3 = xb[(size_t)s3 * 64 + lane];
            unsigned int v4 = xb[(size_t)s4 * 64 + lane];
            unsigned int v5 = xb[(size_t)s5 * 64 + lane];
            unsigned int v6 = xb[(size_t)s6 * 64 + lane];
            unsigned int v7 = xb[(size_t)s7 * 64 + lane];
            ax0 += bf_lo(v0); ay0 += bf_hi(v0);
            ax1 += bf_lo(v1); ay1 += bf_hi(v1);
            ax2 += bf_lo(v2); ay2 += bf_hi(v2);
            ax3 += bf_lo(v3); ay3 += bf_hi(v3);
            ax0 += bf_lo(v4); ay0 += bf_hi(v4);
            ax1 += bf_lo(v5); ay1 += bf_hi(v5);
            ax2 += bf_lo(v6); ay2 += bf_hi(v6);
            ax3 += bf_lo(v7); ay3 += bf_hi(v7);
        } else {
            float2 v0 = x2[(size_t)s0 * 64 + lane];
            float2 v1 = x2[(size_t)s1 * 64 + lane];
            float2 v2 = x2[(size_t)s2 * 64 + lane];
            float2 v3 = x2[(size_t)s3 * 64 + lane];
            float2 v4 = x2[(size_t)s4 * 64 + lane];
            float2 v5 = x2[(size_t)s5 * 64 + lane];
            float2 v6 = x2[(size_t)s6 * 64 + lane];
            float2 v7 = x2[(size_t)s7 * 64 + lane];
            ax0 += v0.x; ay0 += v0.y; ax1 += v1.x; ay1 += v1.y;
            ax2 += v2.x; ay2 += v2.y; ax3 += v3.x; ay3 += v3.y;
            ax0 += v4.x; ay0 += v4.y; ax1 += v5.x; ay1 += v5.y;
            ax2 += v6.x; ay2 += v6.y; ax3 += v7.x; ay3 += v7.y;
        }
    }
    for (; i + 4 <= end; i += 4) {
        int s0 = sorted[i + 0];
        int s1 = sorted[i + 1];
        int s2 = sorted[i + 2];
        int s3 = sorted[i + 3];
        if constexpr (BF) {
            unsigned int v0 = xb[(size_t)s0 * 64 + lane];
            unsigned int v1 = xb[(size_t)s1 * 64 + lane];
            unsigned int v2 = xb[(size_t)s2 * 64 + lane];
            unsigned int v3 = xb[(size_t)s3 * 64 + lane];
            ax0 += bf_lo(v0); ay0 += bf_hi(v0);
            ax1 += bf_lo(v1); ay1 += bf_hi(v1);
            ax2 += bf_lo(v2); ay2 += bf_hi(v2);
            ax3 += bf_lo(v3); ay3 += bf_hi(v3);
        } else {
            float2 v0 = x2[(size_t)s0 * 64 + lane];
            float2 v1 = x2[(size_t)s1 * 64 + lane];
            float2 v2 = x2[(size_t)s2 * 64 + lane];
            float2 v3 = x2[(size_t)s3 * 64 + lane];
            ax0 += v0.x; ay0 += v0.y; ax1 += v1.x; ay1 += v1.y;
            ax2 += v2.x; ay2 += v2.y; ax3 += v3.x; ay3 += v3.y;
        }
    }
    for (; i < end; ++i) {
        int s = sorted[i];
        if constexpr (BF) {
            unsigned int v = xb[(size_t)s * 64 + lane];
            ax0 += bf_lo(v); ay0 += bf_hi(v);
        } else {
            float2 v = x2[(size_t)s * 64 + lane];
            ax0 += v.x; ay0 += v.y;
        }
    }
    float sx = (ax0 + ax1) + (ax2 + ax3);
    float sy = (ay0 + ay1) + (ay2 + ay3);
    unsigned int pk = (unsigned int)f2bf(sx) | ((unsigned int)f2bf(sy) << 16);
    aggb[(size_t)r * 128 + lane] = pk;
}

// ---------------- fused MLP + LayerNorm (32 rows/block) ---------------------
// MFMA operands SWAPPED vs R13: D = mfma(W_frag, A_frag) gives node = lane&15
// (fixed per lane) and 4 CONSECUTIVE output features per acc reg -> each
// thread writes one packed uint2 (4 bf16) / float4 instead of 4 scalar u16/u32
// LDS stores. 4x fewer LDS write instructions; bit-identical math
// (same dot products, same k-order, same ks accumulation order).
template<int K, int RT, bool RELU>
__device__ __forceinline__ void layer_bf16(
    const unsigned short* Hin, int sin,
    const unsigned short* __restrict__ Wt, const float* __restrict__ bias,
    unsigned short* Hout, int sout, int tid)
{
    int lane = tid & 63;
    int w = tid >> 6;
    int r0 = lane & 15, quad = lane >> 4;
    int col0 = w * 32 + r0;            // W fragment rows (features) for acc[.][0]
    int col1 = w * 32 + 16 + r0;       // for acc[.][1]
    int f0 = w * 32 + quad * 4;        // features this thread WRITES from acc[.][0]
    int f1 = w * 32 + 16 + quad * 4;   // from acc[.][1]
    float4 bias0 = *(const float4*)(bias + f0);
    float4 bias1 = *(const float4*)(bias + f1);
    f32x4 acc[RT][2];
#pragma unroll
    for (int rt = 0; rt < RT; ++rt) { acc[rt][0] = 0.f; acc[rt][1] = 0.f; }
    const unsigned short* wrow0 = Wt + col0 * K + quad * 8;
    const unsigned short* wrow1 = Wt + col1 * K + quad * 8;
    const unsigned short* arow = Hin + r0 * sin + quad * 8;
#pragma unroll
    for (int ks = 0; ks < K / 32; ++ks) {
        short8 bf0 = *(const short8*)(wrow0 + ks * 32);
        short8 bf1 = *(const short8*)(wrow1 + ks * 32);
#pragma unroll
        for (int rt = 0; rt < RT; ++rt) {
            short8 af = *(const short8*)(arow + rt * 16 * sin + ks * 32);
            acc[rt][0] = __builtin_amdgcn_mfma_f32_16x16x32_bf16(bf0, af, acc[rt][0], 0, 0, 0);
            acc[rt][1] = __builtin_amdgcn_mfma_f32_16x16x32_bf16(bf1, af, acc[rt][1], 0, 0, 0);
        }
    }
#pragma unroll
    for (int rt = 0; rt < RT; ++rt) {
        int node = rt * 16 + r0;
        float v0 = acc[rt][0][0] + bias0.x;
        float v1 = acc[rt][0][1] + bias0.y;
        float v2 = acc[rt][0][2] + bias0.z;
        float v3 = acc[rt][0][3] + bias0.w;
        float u0 = acc[rt][1][0] + bias1.x;
        float u1 = acc[rt][1][1] + bias1.y;
        float u2 = acc[rt][1][2] + bias1.z;
        float u3 = acc[rt][1][3] + bias1.w;
        if (RELU) {
            v0 = fmaxf(v0, 0.f); v1 = fmaxf(v1, 0.f);
            v2 = fmaxf(v2, 0.f); v3 = fmaxf(v3, 0.f);
            u0 = fmaxf(u0, 0.f); u1 = fmaxf(u1, 0.f);
            u2 = fmaxf(u2, 0.f); u3 = fmaxf(u3, 0.f);
        }
        uint2 p0, p1;
        p0.x = (unsigned int)f2bf(v0) | ((unsigned int)f2bf(v1) << 16);
        p0.y = (unsigned int)f2bf(v2) | ((unsigned int)f2bf(v3) << 16);
        p1.x = (unsigned int)f2bf(u0) | ((unsigned int)f2bf(u1) << 16);
        p1.y = (unsigned int)f2bf(u2) | ((unsigned int)f2bf(u3) << 16);
        *(uint2*)(Hout + node * sout + f0) = p0;
        *(uint2*)(Hout + node * sout + f1) = p1;
    }
}

template<int RT>
__device__ __forceinline__ void layer_f32out(
    const unsigned short* Hin, int sin,
    const unsigned short* __restrict__ Wt, const float* __restrict__ bias,
    float* Hout, int sout, int tid)
{
    constexpr int K = 128;
    int lane = tid & 63;
    int w = tid >> 6;
    int r0 = lane & 15, quad = lane >> 4;
    int col0 = w * 32 + r0;
    int col1 = w * 32 + 16 + r0;
    int f0 = w * 32 + quad * 4;
    int f1 = w * 32 + 16 + quad * 4;
    float4 bias0 = *(const float4*)(bias + f0);
    float4 bias1 = *(const float4*)(bias + f1);
    f32x4 acc[RT][2];
#pragma unroll
    for (int rt = 0; rt < RT; ++rt) { acc[rt][0] = 0.f; acc[rt][1] = 0.f; }
    const unsigned short* wrow0 = Wt + col0 * K + quad * 8;
    const unsigned short* wrow1 = Wt + col1 * K + quad * 8;
    const unsigned short* arow = Hin + r0 * sin + quad * 8;
#pragma unroll
    for (int ks = 0; ks < K / 32; ++ks) {
        short8 bf0 = *(const short8*)(wrow0 + ks * 32);
        short8 bf1 = *(const short8*)(wrow1 + ks * 32);
#pragma unroll
        for (int rt = 0; rt < RT; ++rt) {
            short8 af = *(const short8*)(arow + rt * 16 * sin + ks * 32);
            acc[rt][0] = __builtin_amdgcn_mfma_f32_16x16x32_bf16(bf0, af, acc[rt][0], 0, 0, 0);
            acc[rt][1] = __builtin_amdgcn_mfma_f32_16x16x32_bf16(bf1, af, acc[rt][1], 0, 0, 0);
        }
    }
#pragma unroll
    for (int rt = 0; rt < RT; ++rt) {
        int node = rt * 16 + r0;
        f32x4 o0, o1;
        o0[0] = acc[rt][0][0] + bias0.x;
        o0[1] = acc[rt][0][1] + bias0.y;
        o0[2] = acc[rt][0][2] + bias0.z;
        o0[3] = acc[rt][0][3] + bias0.w;
        o1[0] = acc[rt][1][0] + bias1.x;
        o1[1] = acc[rt][1][1] + bias1.y;
        o1[2] = acc[rt][1][2] + bias1.z;
        o1[3] = acc[rt][1][3] + bias1.w;
        *(f32x4*)(Hout + node * sout + f0) = o0;
        *(f32x4*)(Hout + node * sout + f1) = o1;
    }
}

template<bool BF>
__global__ __launch_bounds__(256) void mlp_kernel(
    const void* __restrict__ xsrc, const uint2* aggb,
    const unsigned short* __restrict__ wt1, const unsigned short* __restrict__ wt2,
    const unsigned short* __restrict__ wt3, const unsigned short* __restrict__ wt4,
    const float* __restrict__ b1, const float* __restrict__ b2,
    const float* __restrict__ b3, const float* __restrict__ b4,
    const float* __restrict__ gamma, const float* __restrict__ beta,
    float4* out4, int N)
{
    __shared__ unsigned char smem[16896 + 8704];
    unsigned short* HA = (unsigned short*)smem;
    unsigned short* HB = (unsigned short*)(smem + 16896);
    float* H4 = (float*)smem;

    int tid = threadIdx.x;
    int node0 = blockIdx.x * 32;

#pragma unroll
    for (int j = 0; j < 4; ++j) {
        int idx = tid + j * 256;           // 0..1023
        int row = idx >> 5, c4 = idx & 31; // 32 rows x 32 chunks of 4 cols
        int node = node0 + row;
        unsigned short* p = HA + row * 264 + c4 * 4;
        if constexpr (BF) {
            uint2 vx = make_uint2(0u, 0u);
            if (node < N) vx = ((const uint2*)xsrc)[(size_t)node * 32 + c4];
            *(uint2*)p = vx;
        } else {
            float4 vx = make_float4(0.f, 0.f, 0.f, 0.f);
            if (node < N) vx = ((const float4*)xsrc)[(size_t)node * 32 + c4];
            p[0] = f2bf(vx.x); p[1] = f2bf(vx.y); p[2] = f2bf(vx.z); p[3] = f2bf(vx.w);
        }
        uint2 va = make_uint2(0u, 0u);
        if (node < N) va = aggb[(size_t)node * 64 + c4];
        *(uint2*)(p + 128) = va;
    }
    __syncthreads();

    layer_bf16<256, 2, true>(HA, 264, wt1, b1, HB, 136, tid);   // h0 -> h1
    __syncthreads();
    layer_bf16<128, 2, true>(HB, 136, wt2, b2, HA, 136, tid);   // h1 -> h2
    __syncthreads();
    layer_bf16<128, 2, true>(HA, 136, wt3, b3, HB, 136, tid);   // h2 -> h3
    __syncthreads();
    layer_f32out<2>(HB, 136, wt4, b4, H4, 132, tid);            // h3 -> h4 (fp32)
    __syncthreads();

    if (tid < 128) {
        int row = tid >> 2;
        int part = tid & 3;
        const float* hr = H4 + row * 132 + part * 32;
        float s = 0.f, s2 = 0.f;
#pragma unroll
        for (int j = 0; j < 8; ++j) {
            float4 v = *(const float4*)(hr + j * 4);
            s  += v.x + v.y + v.z + v.w;
            s2 += v.x * v.x + v.y * v.y + v.z * v.z + v.w * v.w;
        }
        s  += __shfl_xor(s, 1);  s  += __shfl_xor(s, 2);
        s2 += __shfl_xor(s2, 1); s2 += __shfl_xor(s2, 2);
        float mu = s * (1.f / 128.f);
        float var = s2 * (1.f / 128.f) - mu * mu;
        float rstd = rsqrtf(fmaxf(var, 0.f) + LN_EPS);
        int node = node0 + row;
        if (node < N) {
#pragma unroll
            for (int j = 0; j < 8; ++j) {
                int c = part * 32 + j * 4;
                float4 v = *(const float4*)(hr + j * 4);
                float4 o;
                o.x = (v.x - mu) * rstd * gamma[c + 0] + beta[c + 0];
                o.y = (v.y - mu) * rstd * gamma[c + 1] + beta[c + 1];
                o.z = (v.z - mu) * rstd * gamma[c + 2] + beta[c + 2];
                o.w = (v.w - mu) * rstd * gamma[c + 3] + beta[c + 3];
                out4[node * 32 + part * 8 + j] = o;
            }
        }
    }
}

extern "C" void kernel_launch(void* const* d_in, const int* in_sizes, int n_in,
                              void* d_out, int out_size, void* d_ws, size_t ws_size,
                              hipStream_t stream) {
    const float* x     = (const float*)d_in[0];
    const int*   edges = (const int*)d_in[1];
    const float* W1 = (const float*)d_in[2];
    const float* b1 = (const float*)d_in[3];
    const float* W2 = (const float*)d_in[4];
    const float* b2 = (const float*)d_in[5];
    const float* W3 = (const float*)d_in[6];
    const float* b3 = (const float*)d_in[7];
    const float* W4 = (const float*)d_in[8];
    const float* b4 = (const float*)d_in[9];
    const float* gamma = (const float*)d_in[10];
    const float* beta  = (const float*)d_in[11];

    int N = in_sizes[0] / 128;
    int E = in_sizes[1] / 2;

    // agg scratch (packed bf16, 512 B/row stride, 256 B used) lives in d_out:
    // row r's scratch is bytes [512r, 512r+256) of out row r's slot -> row-exact.
    unsigned int* aggb = (unsigned int*)d_out;

    unsigned char* ws = (unsigned char*)d_ws;
    unsigned short* wt1 = (unsigned short*)ws;            // 128x256
    unsigned short* wt2 = wt1 + 128 * 256;                // 128x128
    unsigned short* wt3 = wt2 + 128 * 128;
    unsigned short* wt4 = wt3 + 128 * 128;
    size_t off = (size_t)(128 * 256 + 3 * 128 * 128) * 2; // 163840 B

    size_t packed_bytes = (size_t)E * 4;
    size_t xb_bytes = (size_t)N * 128 * 2;
    size_t region1 = xb_bytes > packed_bytes ? xb_bytes : packed_bytes;
    size_t tail = (size_t)E * 4                 // sorted
                + (size_t)(N + 1) * 4           // offsets
                + (size_t)2 * 256 * NBLK * 4    // BBC + BBL
                + 256 * 4;                      // bucketTotal
    int tier;
    if (ws_size >= off + xb_bytes + packed_bytes + tail + 1024) tier = 2;
    else if (ws_size >= off + region1 + tail + 1024)            tier = 1;
    else                                                        tier = 0;

    unsigned char* p = ws + off;
    unsigned short* xb = nullptr;
    unsigned int* packed;
    if (tier == 2) {
        xb = (unsigned short*)p;  p += xb_bytes;
        packed = (unsigned int*)p; p += packed_bytes;
    } else if (tier == 1) {
        packed = (unsigned int*)p;
        xb = (unsigned short*)p;
        p += region1;
    } else {
        packed = (unsigned int*)p; p += packed_bytes;
    }
    int* sorted = (int*)p;      p += (size_t)E * 4;
    int* offsets = (int*)p;     p += (size_t)(N + 1) * 4;
    int* BBC = (int*)p;         p += (size_t)256 * NBLK * 4;
    int* BBL = (int*)p;         p += (size_t)256 * NBLK * 4;
    int* bucketTotal = (int*)p;

    int chunk = (E + NBLK - 1) / NBLK;

    int total8_now = (tier == 2) ? N * 16 : 0;
    int prep_blocks = (81920 + total8_now + 255) / 256;
    hist_prep_kernel<<<NBLK + prep_blocks, 256, 0, stream>>>(
        edges, BBC, E, chunk,
        W1, W2, W3, W4, wt1, wt2, wt3, wt4,
        (const float4*)x, (uint4*)xb, total8_now);
    bucket_scan1_kernel<<<256, 256, 0, stream>>>(BBC, BBL, bucketTotal);
    bucket_scatter_kernel<<<NBLK, 256, 0, stream>>>(edges, BBL, bucketTotal, packed, E, chunk);
    bucket_sort_kernel<<<256, 256, 0, stream>>>(packed, bucketTotal, offsets, sorted, N);

    if (tier == 1) {
        int total8 = N * 16;
        xcvt_kernel<<<(total8 + 255) / 256, 256, 0, stream>>>(
            (const float4*)x, (uint4*)xb, total8);
    }

    int agg_blocks = (N + 3) / 4;
    if (tier >= 1)
        aggregate_kernel<true><<<agg_blocks, 256, 0, stream>>>(
            (const void*)xb, offsets, sorted, aggb, N);
    else
        aggregate_kernel<false><<<agg_blocks, 256, 0, stream>>>(
            (const void*)x, offsets, sorted, aggb, N);

    int mlp_blocks = (N + 31) / 32;
    if (tier >= 1)
        mlp_kernel<true><<<mlp_blocks, 256, 0, stream>>>(
            (const void*)xb, (const uint2*)aggb,
            wt1, wt2, wt3, wt4, b1, b2, b3, b4, gamma, beta,
            (float4*)d_out, N);
    else
        mlp_kernel<false><<<mlp_blocks, 256, 0, stream>>>(
            (const void*)x, (const uint2*)aggb,
            wt1, wt2, wt3, wt4, b1, b2, b3, b4, gamma, beta,
            (float4*)d_out, N);
}

// Round 15
// 202.159 us; speedup vs baseline: 1.0125x; 1.0125x over previous
//
#include <hip/hip_runtime.h>
#include <hip/hip_bf16.h>

typedef short short8 __attribute__((ext_vector_type(8)));
typedef float f32x4 __attribute__((ext_vector_type(4)));

#define LN_EPS 1e-5f
#define NBLK 512   // chunk blocks for hist/scatter (2 blocks/CU); must match scan1

__device__ __forceinline__ unsigned short f2bf(float f) {
    unsigned int u = __builtin_bit_cast(unsigned int, f);
    unsigned int r = (u + 0x7FFFu + ((u >> 16) & 1u)) >> 16;
    return (unsigned short)r;
}
__device__ __forceinline__ float bf_lo(unsigned int v) {
    return __builtin_bit_cast(float, v << 16);
}
__device__ __forceinline__ float bf_hi(unsigned int v) {
    return __builtin_bit_cast(float, v & 0xFFFF0000u);
}

__device__ __forceinline__ bool edges_are_i64(const int* ei) {
    return ((ei[1] | ei[3] | ei[5] | ei[7]) == 0);
}

// ---------------- shared device bodies --------------------------------------
__device__ __forceinline__ void do_hist(
    const int* __restrict__ ei, int* __restrict__ BBC, int E, int chunk,
    int blk, int t, int* hist)
{
    hist[t] = 0;
    __syncthreads();
    int beg = blk * chunk;
    int end = min(E, beg + chunk);
    if (edges_are_i64(ei)) {
        const long long* e64 = (const long long*)ei;
        for (int e = beg + t; e < end; e += 256)
            atomicAdd(&hist[((int)e64[E + e]) >> 8], 1);
    } else {
        for (int e = beg + t; e < end; e += 256)
            atomicAdd(&hist[ei[E + e] >> 8], 1);
    }
    __syncthreads();
    BBC[t * NBLK + blk] = hist[t];
}

__device__ __forceinline__ void do_prep(
    const float* __restrict__ W1, const float* __restrict__ W2,
    const float* __restrict__ W3, const float* __restrict__ W4,
    unsigned short* __restrict__ wt1, unsigned short* __restrict__ wt2,
    unsigned short* __restrict__ wt3, unsigned short* __restrict__ wt4,
    const float4* __restrict__ x4, uint4* __restrict__ xb4, int total8,
    int idx)
{
    if (idx < 32768) {                       // W1: 256x128
        int k = idx >> 7, n = idx & 127;
        wt1[n * 256 + k] = f2bf(W1[idx]);
    } else if (idx < 49152) {                // W2: 128x128
        int j = idx - 32768; int k = j >> 7, n = j & 127;
        wt2[n * 128 + k] = f2bf(W2[j]);
    } else if (idx < 65536) {                // W3
        int j = idx - 49152; int k = j >> 7, n = j & 127;
        wt3[n * 128 + k] = f2bf(W3[j]);
    } else if (idx < 81920) {                // W4
        int j = idx - 65536; int k = j >> 7, n = j & 127;
        wt4[n * 128 + k] = f2bf(W4[j]);
    } else {
        int i = idx - 81920;
        if (i < total8) {                    // x -> bf16 (8 elems per thread)
            float4 a = x4[i * 2], b = x4[i * 2 + 1];
            uint4 o;
            o.x = (unsigned int)f2bf(a.x) | ((unsigned int)f2bf(a.y) << 16);
            o.y = (unsigned int)f2bf(a.z) | ((unsigned int)f2bf(a.w) << 16);
            o.z = (unsigned int)f2bf(b.x) | ((unsigned int)f2bf(b.y) << 16);
            o.w = (unsigned int)f2bf(b.z) | ((unsigned int)f2bf(b.w) << 16);
            xb4[i] = o;
        }
    }
}

// ---------------- merged: hist (blocks < NBLK) + prep (blocks >= NBLK) ------
__global__ __launch_bounds__(256) void hist_prep_kernel(
    const int* __restrict__ ei, int* __restrict__ BBC, int E, int chunk,
    const float* __restrict__ W1, const float* __restrict__ W2,
    const float* __restrict__ W3, const float* __restrict__ W4,
    unsigned short* __restrict__ wt1, unsigned short* __restrict__ wt2,
    unsigned short* __restrict__ wt3, unsigned short* __restrict__ wt4,
    const float4* __restrict__ x4, uint4* __restrict__ xb4, int total8)
{
    __shared__ int sh[256];
    int t = threadIdx.x;
    if (blockIdx.x < NBLK) {
        do_hist(ei, BBC, E, chunk, blockIdx.x, t, sh);
    } else {
        do_prep(W1, W2, W3, W4, wt1, wt2, wt3, wt4, x4, xb4, total8,
                (blockIdx.x - NBLK) * 256 + t);
    }
}

// ---------------- x fp32 -> bf16 (tier-1 only: runs after sort) -------------
__global__ __launch_bounds__(256) void xcvt_kernel(
    const float4* __restrict__ x4, uint4* __restrict__ xb4, int total8)
{
    int i = blockIdx.x * 256 + threadIdx.x;
    if (i >= total8) return;
    float4 a = x4[i * 2], b = x4[i * 2 + 1];
    uint4 o;
    o.x = (unsigned int)f2bf(a.x) | ((unsigned int)f2bf(a.y) << 16);
    o.y = (unsigned int)f2bf(a.z) | ((unsigned int)f2bf(a.w) << 16);
    o.z = (unsigned int)f2bf(b.x) | ((unsigned int)f2bf(b.y) << 16);
    o.w = (unsigned int)f2bf(b.z) | ((unsigned int)f2bf(b.w) << 16);
    xb4[i] = o;
}

// S1: per-bucket exclusive scan across NBLK=512 chunk counts (2 per thread)
__global__ __launch_bounds__(256) void bucket_scan1_kernel(
    const int* __restrict__ BBC, int* __restrict__ BBL, int* __restrict__ bucketTotal)
{
    __shared__ int sd[256];
    int t = threadIdx.x, b = blockIdx.x;
    int v0 = BBC[b * NBLK + 2 * t];
    int v1 = BBC[b * NBLK + 2 * t + 1];
    int pair = v0 + v1;
    sd[t] = pair;
    __syncthreads();
    for (int d = 1; d < 256; d <<= 1) {
        int add = (t >= d) ? sd[t - d] : 0;
        __syncthreads();
        sd[t] += add;
        __syncthreads();
    }
    int excl = sd[t] - pair;                 // sum of chunks < 2t
    BBL[b * NBLK + 2 * t]     = excl;
    BBL[b * NBLK + 2 * t + 1] = excl + v0;
    if (t == 255) bucketTotal[b] = sd[255];
}

// B: scatter edges into coarse-bucket regions (LDS cursors, plain stores)
//    bucket bases recomputed in-LDS from bucketTotal (scan2 folded in).
//    packed word = sender (24 bits) | r_local (top 8 bits)
__global__ __launch_bounds__(256) void bucket_scatter_kernel(
    const int* __restrict__ ei, const int* __restrict__ BBL,
    const int* __restrict__ bucketTotal, unsigned int* __restrict__ packed,
    int E, int chunk)
{
    __shared__ int cur[256];
    __shared__ int sd[256];
    int t = threadIdx.x, blk = blockIdx.x;
    int v = bucketTotal[t];
    sd[t] = v;
    __syncthreads();
    for (int d = 1; d < 256; d <<= 1) {
        int add = (t >= d) ? sd[t - d] : 0;
        __syncthreads();
        sd[t] += add;
        __syncthreads();
    }
    cur[t] = (sd[t] - v) + BBL[t * NBLK + blk];  // bucketBase[t] + within-bucket off
    __syncthreads();
    int beg = blk * chunk;
    int end = min(E, beg + chunk);
    if (edges_are_i64(ei)) {
        const long long* e64 = (const long long*)ei;
        for (int e = beg + t; e < end; e += 256) {
            int s = (int)e64[e], r = (int)e64[E + e];
            int pos = atomicAdd(&cur[r >> 8], 1);
            packed[pos] = (unsigned int)s | ((unsigned int)(r & 255) << 24);
        }
    } else {
        for (int e = beg + t; e < end; e += 256) {
            int s = ei[e], r = ei[E + e];
            int pos = atomicAdd(&cur[r >> 8], 1);
            packed[pos] = (unsigned int)s | ((unsigned int)(r & 255) << 24);
        }
    }
}

// C: per-bucket fine counting sort -> offsets[] and sorted[] (senders)
//    bucket base recomputed in-LDS from bucketTotal (scan2 folded in).
__global__ __launch_bounds__(256) void bucket_sort_kernel(
    const unsigned int* __restrict__ packed, const int* __restrict__ bucketTotal,
    int* __restrict__ offsets, int* __restrict__ sorted, int N)
{
    __shared__ int hist[256];
    __shared__ int sd[256];
    __shared__ int base[256];
    int t = threadIdx.x, b = blockIdx.x;
    int bv = bucketTotal[t];
    sd[t] = bv;
    __syncthreads();
    for (int d = 1; d < 256; d <<= 1) {
        int add = (t >= d) ? sd[t - d] : 0;
        __syncthreads();
        sd[t] += add;
        __syncthreads();
    }
    base[t] = sd[t] - bv;                    // exclusive bucket base
    __syncthreads();
    int beg = base[b];
    int end = beg + bucketTotal[b];
    hist[t] = 0;
    __syncthreads();
    for (int i = beg + t; i < end; i += 256)
        atomicAdd(&hist[packed[i] >> 24], 1);
    __syncthreads();
    int v = hist[t];
    sd[t] = v;
    __syncthreads();
    for (int d = 1; d < 256; d <<= 1) {
        int add = (t >= d) ? sd[t - d] : 0;
        __syncthreads();
        sd[t] += add;
        __syncthreads();
    }
    int excl = sd[t] - v;
    int idx = b * 256 + t;
    if (idx <= N) offsets[idx] = beg + excl;   // idx==N lands here too (== E)
    hist[t] = excl;                            // reuse as LDS cursor
    __syncthreads();
    for (int i = beg + t; i < end; i += 256) {
        unsigned int p = packed[i];
        int rl = (int)(p >> 24);
        int pos = beg + atomicAdd(&hist[rl], 1);
        sorted[pos] = (int)(p & 0xFFFFFFu);
    }
}

// ---------------- atomic-free segmented aggregation ----------------
template<bool BF>
__global__ __launch_bounds__(256) void aggregate_kernel(
    const void* __restrict__ xsrc, const int* __restrict__ offsets,
    const int* __restrict__ sorted, unsigned int* __restrict__ aggb, int N)
{
    int wave = threadIdx.x >> 6, lane = threadIdx.x & 63;
    int r = blockIdx.x * 4 + wave;
    if (r >= N) return;
    int beg = offsets[r], end = offsets[r + 1];
    const unsigned int* xb = (const unsigned int*)xsrc;
    const float2* x2 = (const float2*)xsrc;
    float ax0 = 0, ay0 = 0, ax1 = 0, ay1 = 0;
    float ax2 = 0, ay2 = 0, ax3 = 0, ay3 = 0;
    int i = beg;
    for (; i + 8 <= end; i += 8) {
        int s0 = sorted[i + 0];
        int s1 = sorted[i + 1];
        int s2 = sorted[i + 2];
        int s3 = sorted[i + 3];
        int s4 = sorted[i + 4];
        int s5 = sorted[i + 5];
        int s6 = sorted[i + 6];
        int s7 = sorted[i + 7];
        if constexpr (BF) {
            unsigned int v0 = xb[(size_t)s0 * 64 + lane];
            unsigned int v1 = xb[(size_t)s1 * 64 + lane];
            unsigned int v2 = xb[(size_t)s2 * 64 + lane];
            unsigned int v3 = xb[(size_t)s3 * 64 + lane];
            unsigned int v4 = xb[(size_t)s4 * 64 + lane];
            unsigned int v5 = xb[(size_t)s5 * 64 + lane];
            unsigned int v6 = xb[(size_t)s6 * 64 + lane];
            unsigned int v7 = xb[(size_t)s7 * 64 + lane];
            ax0 += bf_lo(v0); ay0 += bf_hi(v0);
            ax1 += bf_lo(v1); ay1 += bf_hi(v1);
            ax2 += bf_lo(v2); ay2 += bf_hi(v2);
            ax3 += bf_lo(v3); ay3 += bf_hi(v3);
            ax0 += bf_lo(v4); ay0 += bf_hi(v4);
            ax1 += bf_lo(v5); ay1 += bf_hi(v5);
            ax2 += bf_lo(v6); ay2 += bf_hi(v6);
            ax3 += bf_lo(v7); ay3 += bf_hi(v7);
        } else {
            float2 v0 = x2[(size_t)s0 * 64 + lane];
            float2 v1 = x2[(size_t)s1 * 64 + lane];
            float2 v2 = x2[(size_t)s2 * 64 + lane];
            float2 v3 = x2[(size_t)s3 * 64 + lane];
            float2 v4 = x2[(size_t)s4 * 64 + lane];
            float2 v5 = x2[(size_t)s5 * 64 + lane];
            float2 v6 = x2[(size_t)s6 * 64 + lane];
            float2 v7 = x2[(size_t)s7 * 64 + lane];
            ax0 += v0.x; ay0 += v0.y; ax1 += v1.x; ay1 += v1.y;
            ax2 += v2.x; ay2 += v2.y; ax3 += v3.x; ay3 += v3.y;
            ax0 += v4.x; ay0 += v4.y; ax1 += v5.x; ay1 += v5.y;
            ax2 += v6.x; ay2 += v6.y; ax3 += v7.x; ay3 += v7.y;
        }
    }
    for (; i + 4 <= end; i += 4) {
        int s0 = sorted[i + 0];
        int s1 = sorted[i + 1];
        int s2 = sorted[i + 2];
        int s3 = sorted[i + 3];
        if constexpr (BF) {
            unsigned int v0 = xb[(size_t)s0 * 64 + lane];
            unsigned int v1 = xb[(size_t)s1 * 64 + lane];
            unsigned int v2 = xb[(size_t)s2 * 64 + lane];
            unsigned int v3 = xb[(size_t)s3 * 64 + lane];
            ax0 += bf_lo(v0); ay0 += bf_hi(v0);
            ax1 += bf_lo(v1); ay1 += bf_hi(v1);
            ax2 += bf_lo(v2); ay2 += bf_hi(v2);
            ax3 += bf_lo(v3); ay3 += bf_hi(v3);
        } else {
            float2 v0 = x2[(size_t)s0 * 64 + lane];
            float2 v1 = x2[(size_t)s1 * 64 + lane];
            float2 v2 = x2[(size_t)s2 * 64 + lane];
            float2 v3 = x2[(size_t)s3 * 64 + lane];
            ax0 += v0.x; ay0 += v0.y; ax1 += v1.x; ay1 += v1.y;
            ax2 += v2.x; ay2 += v2.y; ax3 += v3.x; ay3 += v3.y;
        }
    }
    for (; i < end; ++i) {
        int s = sorted[i];
        if constexpr (BF) {
            unsigned int v = xb[(size_t)s * 64 + lane];
            ax0 += bf_lo(v); ay0 += bf_hi(v);
        } else {
            float2 v = x2[(size_t)s * 64 + lane];
            ax0 += v.x; ay0 += v.y;
        }
    }
    float sx = (ax0 + ax1) + (ax2 + ax3);
    float sy = (ay0 + ay1) + (ay2 + ay3);
    unsigned int pk = (unsigned int)f2bf(sx) | ((unsigned int)f2bf(sy) << 16);
    aggb[(size_t)r * 128 + lane] = pk;
}

// ---------------- fused MLP + LayerNorm (32 rows/block, R13-proven) ---------
template<int K, int RT, bool RELU>
__device__ __forceinline__ void layer_bf16(
    const unsigned short* Hin, int sin,
    const unsigned short* __restrict__ Wt, const float* __restrict__ bias,
    unsigned short* Hout, int sout, int tid)
{
    int lane = tid & 63;
    int w = tid >> 6;
    int r0 = lane & 15, quad = lane >> 4;
    int col0 = w * 32 + r0;
    int col1 = w * 32 + 16 + r0;
    float bias0 = bias[col0], bias1 = bias[col1];
    f32x4 acc[RT][2];
#pragma unroll
    for (int rt = 0; rt < RT; ++rt) { acc[rt][0] = 0.f; acc[rt][1] = 0.f; }
    const unsigned short* wrow0 = Wt + col0 * K + quad * 8;
    const unsigned short* wrow1 = Wt + col1 * K + quad * 8;
    const unsigned short* arow = Hin + r0 * sin + quad * 8;
#pragma unroll
    for (int ks = 0; ks < K / 32; ++ks) {
        short8 bf0 = *(const short8*)(wrow0 + ks * 32);
        short8 bf1 = *(const short8*)(wrow1 + ks * 32);
#pragma unroll
        for (int rt = 0; rt < RT; ++rt) {
            short8 af = *(const short8*)(arow + rt * 16 * sin + ks * 32);
            acc[rt][0] = __builtin_amdgcn_mfma_f32_16x16x32_bf16(af, bf0, acc[rt][0], 0, 0, 0);
            acc[rt][1] = __builtin_amdgcn_mfma_f32_16x16x32_bf16(af, bf1, acc[rt][1], 0, 0, 0);
        }
    }
#pragma unroll
    for (int rt = 0; rt < RT; ++rt) {
#pragma unroll
        for (int i = 0; i < 4; ++i) {
            int row = rt * 16 + quad * 4 + i;
            float v0 = acc[rt][0][i] + bias0;
            float v1 = acc[rt][1][i] + bias1;
            if (RELU) { v0 = fmaxf(v0, 0.f); v1 = fmaxf(v1, 0.f); }
            Hout[row * sout + col0] = f2bf(v0);
            Hout[row * sout + col1] = f2bf(v1);
        }
    }
}

template<int RT>
__device__ __forceinline__ void layer_f32out(
    const unsigned short* Hin, int sin,
    const unsigned short* __restrict__ Wt, const float* __restrict__ bias,
    float* Hout, int sout, int tid)
{
    constexpr int K = 128;
    int lane = tid & 63;
    int w = tid >> 6;
    int r0 = lane & 15, quad = lane >> 4;
    int col0 = w * 32 + r0;
    int col1 = w * 32 + 16 + r0;
    float bias0 = bias[col0], bias1 = bias[col1];
    f32x4 acc[RT][2];
#pragma unroll
    for (int rt = 0; rt < RT; ++rt) { acc[rt][0] = 0.f; acc[rt][1] = 0.f; }
    const unsigned short* wrow0 = Wt + col0 * K + quad * 8;
    const unsigned short* wrow1 = Wt + col1 * K + quad * 8;
    const unsigned short* arow = Hin + r0 * sin + quad * 8;
#pragma unroll
    for (int ks = 0; ks < K / 32; ++ks) {
        short8 bf0 = *(const short8*)(wrow0 + ks * 32);
        short8 bf1 = *(const short8*)(wrow1 + ks * 32);
#pragma unroll
        for (int rt = 0; rt < RT; ++rt) {
            short8 af = *(const short8*)(arow + rt * 16 * sin + ks * 32);
            acc[rt][0] = __builtin_amdgcn_mfma_f32_16x16x32_bf16(af, bf0, acc[rt][0], 0, 0, 0);
            acc[rt][1] = __builtin_amdgcn_mfma_f32_16x16x32_bf16(af, bf1, acc[rt][1], 0, 0, 0);
        }
    }
#pragma unroll
    for (int rt = 0; rt < RT; ++rt) {
#pragma unroll
        for (int i = 0; i < 4; ++i) {
            int row = rt * 16 + quad * 4 + i;
            Hout[row * sout + col0] = acc[rt][0][i] + bias0;
            Hout[row * sout + col1] = acc[rt][1][i] + bias1;
        }
    }
}

template<bool BF>
__global__ __launch_bounds__(256) void mlp_kernel(
    const void* __restrict__ xsrc, const uint2* aggb,
    const unsigned short* __restrict__ wt1, const unsigned short* __restrict__ wt2,
    const unsigned short* __restrict__ wt3, const unsigned short* __restrict__ wt4,
    const float* __restrict__ b1, const float* __restrict__ b2,
    const float* __restrict__ b3, const float* __restrict__ b4,
    const float* __restrict__ gamma, const float* __restrict__ beta,
    float4* out4, int N)
{
    __shared__ unsigned char smem[16896 + 8704];
    unsigned short* HA = (unsigned short*)smem;
    unsigned short* HB = (unsigned short*)(smem + 16896);
    float* H4 = (float*)smem;

    int tid = threadIdx.x;
    int node0 = blockIdx.x * 32;

#pragma unroll
    for (int j = 0; j < 4; ++j) {
        int idx = tid + j * 256;           // 0..1023
        int row = idx >> 5, c4 = idx & 31; // 32 rows x 32 chunks of 4 cols
        int node = node0 + row;
        unsigned short* p = HA + row * 264 + c4 * 4;
        if constexpr (BF) {
            uint2 vx = make_uint2(0u, 0u);
            if (node < N) vx = ((const uint2*)xsrc)[(size_t)node * 32 + c4];
            *(uint2*)p = vx;
        } else {
            float4 vx = make_float4(0.f, 0.f, 0.f, 0.f);
            if (node < N) vx = ((const float4*)xsrc)[(size_t)node * 32 + c4];
            p[0] = f2bf(vx.x); p[1] = f2bf(vx.y); p[2] = f2bf(vx.z); p[3] = f2bf(vx.w);
        }
        uint2 va = make_uint2(0u, 0u);
        if (node < N) va = aggb[(size_t)node * 64 + c4];
        *(uint2*)(p + 128) = va;
    }
    __syncthreads();

    layer_bf16<256, 2, true>(HA, 264, wt1, b1, HB, 136, tid);   // h0 -> h1
    __syncthreads();
    layer_bf16<128, 2, true>(HB, 136, wt2, b2, HA, 136, tid);   // h1 -> h2
    __syncthreads();
    layer_bf16<128, 2, true>(HA, 136, wt3, b3, HB, 136, tid);   // h2 -> h3
    __syncthreads();
    layer_f32out<2>(HB, 136, wt4, b4, H4, 132, tid);            // h3 -> h4 (fp32)
    __syncthreads();

    if (tid < 128) {
        int row = tid >> 2;
        int part = tid & 3;
        const float* hr = H4 + row * 132 + part * 32;
        float s = 0.f, s2 = 0.f;
#pragma unroll
        for (int j = 0; j < 8; ++j) {
            float4 v = *(const float4*)(hr + j * 4);
            s  += v.x + v.y + v.z + v.w;
            s2 += v.x * v.x + v.y * v.y + v.z * v.z + v.w * v.w;
        }
        s  += __shfl_xor(s, 1);  s  += __shfl_xor(s, 2);
        s2 += __shfl_xor(s2, 1); s2 += __shfl_xor(s2, 2);
        float mu = s * (1.f / 128.f);
        float var = s2 * (1.f / 128.f) - mu * mu;
        float rstd = rsqrtf(fmaxf(var, 0.f) + LN_EPS);
        int node = node0 + row;
        if (node < N) {
#pragma unroll
            for (int j = 0; j < 8; ++j) {
                int c = part * 32 + j * 4;
                float4 v = *(const float4*)(hr + j * 4);
                float4 o;
                o.x = (v.x - mu) * rstd * gamma[c + 0] + beta[c + 0];
                o.y = (v.y - mu) * rstd * gamma[c + 1] + beta[c + 1];
                o.z = (v.z - mu) * rstd * gamma[c + 2] + beta[c + 2];
                o.w = (v.w - mu) * rstd * gamma[c + 3] + beta[c + 3];
                out4[node * 32 + part * 8 + j] = o;
            }
        }
    }
}

extern "C" void kernel_launch(void* const* d_in, const int* in_sizes, int n_in,
                              void* d_out, int out_size, void* d_ws, size_t ws_size,
                              hipStream_t stream) {
    const float* x     = (const float*)d_in[0];
    const int*   edges = (const int*)d_in[1];
    const float* W1 = (const float*)d_in[2];
    const float* b1 = (const float*)d_in[3];
    const float* W2 = (const float*)d_in[4];
    const float* b2 = (const float*)d_in[5];
    const float* W3 = (const float*)d_in[6];
    const float* b3 = (const float*)d_in[7];
    const float* W4 = (const float*)d_in[8];
    const float* b4 = (const float*)d_in[9];
    const float* gamma = (const float*)d_in[10];
    const float* beta  = (const float*)d_in[11];

    int N = in_sizes[0] / 128;
    int E = in_sizes[1] / 2;

    // agg scratch (packed bf16, 512 B/row stride, 256 B used) lives in d_out:
    // row r's scratch is bytes [512r, 512r+256) of out row r's slot -> row-exact.
    unsigned int* aggb = (unsigned int*)d_out;

    unsigned char* ws = (unsigned char*)d_ws;
    unsigned short* wt1 = (unsigned short*)ws;            // 128x256
    unsigned short* wt2 = wt1 + 128 * 256;                // 128x128
    unsigned short* wt3 = wt2 + 128 * 128;
    unsigned short* wt4 = wt3 + 128 * 128;
    size_t off = (size_t)(128 * 256 + 3 * 128 * 128) * 2; // 163840 B

    size_t packed_bytes = (size_t)E * 4;
    size_t xb_bytes = (size_t)N * 128 * 2;
    size_t region1 = xb_bytes > packed_bytes ? xb_bytes : packed_bytes;
    size_t tail = (size_t)E * 4                 // sorted
                + (size_t)(N + 1) * 4           // offsets
                + (size_t)2 * 256 * NBLK * 4    // BBC + BBL
                + 256 * 4;                      // bucketTotal
    int tier;
    if (ws_size >= off + xb_bytes + packed_bytes + tail + 1024) tier = 2;
    else if (ws_size >= off + region1 + tail + 1024)            tier = 1;
    else                                                        tier = 0;

    unsigned char* p = ws + off;
    unsigned short* xb = nullptr;
    unsigned int* packed;
    if (tier == 2) {
        xb = (unsigned short*)p;  p += xb_bytes;
        packed = (unsigned int*)p; p += packed_bytes;
    } else if (tier == 1) {
        packed = (unsigned int*)p;
        xb = (unsigned short*)p;
        p += region1;
    } else {
        packed = (unsigned int*)p; p += packed_bytes;
    }
    int* sorted = (int*)p;      p += (size_t)E * 4;
    int* offsets = (int*)p;     p += (size_t)(N + 1) * 4;
    int* BBC = (int*)p;         p += (size_t)256 * NBLK * 4;
    int* BBL = (int*)p;         p += (size_t)256 * NBLK * 4;
    int* bucketTotal = (int*)p;

    int chunk = (E + NBLK - 1) / NBLK;

    int total8_now = (tier == 2) ? N * 16 : 0;
    int prep_blocks = (81920 + total8_now + 255) / 256;
    hist_prep_kernel<<<NBLK + prep_blocks, 256, 0, stream>>>(
        edges, BBC, E, chunk,
        W1, W2, W3, W4, wt1, wt2, wt3, wt4,
        (const float4*)x, (uint4*)xb, total8_now);
    bucket_scan1_kernel<<<256, 256, 0, stream>>>(BBC, BBL, bucketTotal);
    bucket_scatter_kernel<<<NBLK, 256, 0, stream>>>(edges, BBL, bucketTotal, packed, E, chunk);
    bucket_sort_kernel<<<256, 256, 0, stream>>>(packed, bucketTotal, offsets, sorted, N);

    if (tier == 1) {
        int total8 = N * 16;
        xcvt_kernel<<<(total8 + 255) / 256, 256, 0, stream>>>(
            (const float4*)x, (uint4*)xb, total8);
    }

    int agg_blocks = (N + 3) / 4;
    if (tier >= 1)
        aggregate_kernel<true><<<agg_blocks, 256, 0, stream>>>(
            (const void*)xb, offsets, sorted, aggb, N);
    else
        aggregate_kernel<false><<<agg_blocks, 256, 0, stream>>>(
            (const void*)x, offsets, sorted, aggb, N);

    int mlp_blocks = (N + 31) / 32;
    if (tier >= 1)
        mlp_kernel<true><<<mlp_blocks, 256, 0, stream>>>(
            (const void*)xb, (const uint2*)aggb,
            wt1, wt2, wt3, wt4, b1, b2, b3, b4, gamma, beta,
            (float4*)d_out, N);
    else
        mlp_kernel<false><<<mlp_blocks, 256, 0, stream>>>(
            (const void*)x, (const uint2*)aggb,
            wt1, wt2, wt3, wt4, b1, b2, b3, b4, gamma, beta,
            (float4*)d_out, N);
}